// Round 15
// baseline (412.040 us; speedup 1.0000x reference)
//
#include <hip/hip_runtime.h>
#include <hip/hip_bf16.h>

typedef __attribute__((ext_vector_type(4))) float f32x4;
typedef __attribute__((ext_vector_type(2))) unsigned int u32x2;
typedef __attribute__((ext_vector_type(8))) short s16x8;
typedef __attribute__((ext_vector_type(8))) __bf16 bf16v8;
typedef __attribute__((ext_vector_type(8))) _Float16 f16v8;
typedef __attribute__((ext_vector_type(4))) _Float16 f16x4;

// LDS layout (bytes) — 80 KB => 2 blocks/CU while keeping 2 waves/SIMD (256-reg budget)
#define LDS_X  0        // 32768: x window bf16 [64][256] swz512 (live until half-2 phase 1)
#define LDS_Q  32768    // 16384: Q-half bf16 [64][128] swz256; attn fp16 after phase 2
#define LDS_K  49152    // 16384: K-half bf16 [64][128] swz256
#define LDS_VT 65536    // 16384: V^T-half fp16 [128][64] swz128
#define LDS_TOT 81920

__device__ __forceinline__ f32x4 mfma16(s16x8 a, s16x8 b, f32x4 c) {
  return __builtin_amdgcn_mfma_f32_16x16x32_bf16(
      __builtin_bit_cast(bf16v8, a), __builtin_bit_cast(bf16v8, b), c, 0, 0, 0);
}
__device__ __forceinline__ f32x4 mfma16h(s16x8 a, s16x8 b, f32x4 c) {
  return __builtin_amdgcn_mfma_f32_16x16x32_f16(
      __builtin_bit_cast(f16v8, a), __builtin_bit_cast(f16v8, b), c, 0, 0, 0);
}
__device__ __forceinline__ f32x4 mfmah16(f16x4 a, f16x4 b, f32x4 c) {
  return __builtin_amdgcn_mfma_f32_16x16x16f16(a, b, c, 0, 0, 0);
}

// HW pair converts
__device__ __forceinline__ unsigned int cvt2(float a, float b) {   // 2x bf16, RNE
  __hip_bfloat162 r = __float22bfloat162_rn(make_float2(a, b));
  unsigned int u;
  __builtin_memcpy(&u, &r, 4);
  return u;
}
__device__ __forceinline__ unsigned int cvt2h(float a, float b) {  // 2x fp16, RTZ
  auto r = __builtin_amdgcn_cvt_pkrtz(a, b);
  unsigned int u;
  __builtin_memcpy(&u, &r, 4);
  return u;
}
__device__ __forceinline__ f16x4 pack4h(float a, float b, float c, float d) {
  u32x2 u;
  u.x = cvt2h(a, b);
  u.y = cvt2h(c, d);
  f16x4 r;
  __builtin_memcpy(&r, &u, 8);
  return r;
}

__device__ __forceinline__ short f2bf(float f) {
  unsigned u = __float_as_uint(f);
  u += 0x7fffu + ((u >> 16) & 1u);
  return (short)(u >> 16);
}

__device__ __forceinline__ int swz512(int row, int colByte) {
  return row * 512 + (colByte ^ ((row & 7) << 4));
}
__device__ __forceinline__ int swz256(int row, int colByte) {
  return row * 256 + (colByte ^ ((row & 7) << 4));
}
__device__ __forceinline__ int swz128(int row, int colByte) {
  return row * 128 + (colByte ^ ((row & 7) << 4));
}

// Prep: WqkvT[n][k] bf16 (768x256); WoutT[n][k] fp16 (256x256);
// RELT[var][h][qt][strip][lane][r] f32 = masked rel_pos in simT C-frag order.
__global__ void prep_w(const float* __restrict__ Wqkv, const float* __restrict__ Wout,
                       const float* __restrict__ relp,
                       short* __restrict__ wqkvT, short* __restrict__ wH,
                       float* __restrict__ relt) {
  int t = blockIdx.x * 256 + threadIdx.x;
  if (t < 768 * 256) {
    int n = t >> 8, k = t & 255;
    wqkvT[t] = f2bf(Wqkv[k * 768 + n]);
  } else if (t < 768 * 256 + 256 * 256) {
    int t2 = t - 768 * 256;
    int n = t2 >> 8, k = t2 & 255;
    _Float16 h = (_Float16)Wout[k * 256 + n];
    unsigned short us;
    __builtin_memcpy(&us, &h, 2);
    wH[t2] = (short)us;
  } else {
    int u = t - 768 * 256 - 256 * 256;   // 0 .. 131071
    int r = u & 3, l = (u >> 2) & 63, strip = (u >> 8) & 3;
    int qt = (u >> 10) & 3, h = (u >> 12) & 7, var = (u >> 15) & 3;
    int p = strip * 16 + (l & 15);
    int q = qt * 16 + ((l >> 4) << 2) + r;
    int pi = p >> 3, pj = p & 7, qi = q >> 3, qj = q & 7;
    bool mrow = (var >> 1) & 1, mcol = var & 1;
    bool mk = (mrow && ((pi < 4) != (qi < 4))) || (mcol && ((pj < 4) != (qj < 4)));
    relt[u] = mk ? -1e30f : relp[h * 225 + (pi - qi + 7) * 15 + (pj - qj + 7)];
  }
}

// One block per (batch, window). 256 threads = 4 waves. 80 KB LDS => 2 blocks/CU,
// still 2 waves/SIMD (256-reg budget, no spills) but the two waves on a SIMD come
// from INDEPENDENT blocks -> barrier drains and memory phases overlap across blocks.
__global__ __launch_bounds__(256, 2) void swin_mfma(
    const float* __restrict__ x, const float* __restrict__ bqkv,
    const float* __restrict__ bout,
    const short* __restrict__ wqkvT, const short* __restrict__ wH,
    const float* __restrict__ relt, float* __restrict__ out)
{
  __shared__ __align__(16) char lds[LDS_TOT];

  const int tx = threadIdx.x;
  const int w  = tx >> 6;         // wave 0..3
  const int l  = tx & 63;         // lane
  const int g  = l >> 4;          // k-group 0..3
  const int li = l & 15;          // row/col within fragment

  const int b   = blockIdx.x >> 10;
  const int wdw = blockIdx.x & 1023;
  const int wh  = wdw >> 5, wwi = wdw & 31;
  const int rvar = ((wh == 31) ? 2 : 0) | ((wwi == 31) ? 1 : 0);

  // ---- Phase 0: stage x window (rolled -4) as bf16 into LDS ----
  for (int i = 0; i < 16; ++i) {
    int idx = tx + i * 256;       // 0..4095
    int p = idx >> 6, c4 = idx & 63;
    int pi = p >> 3, pj = p & 7;
    int sr = (wh * 8 + pi + 4) & 255;
    int sc = (wwi * 8 + pj + 4) & 255;
    f32x4 v = *(const f32x4*)(x + ((((size_t)b * 256 + sr) * 256 + sc) * 256 + c4 * 4));
    u32x2 uu;
    uu.x = cvt2(v[0], v[1]);
    uu.y = cvt2(v[2], v[3]);
    *(u32x2*)(lds + LDS_X + swz512(p, c4 * 8)) = uu;
  }
  __syncthreads();

  f32x4 acc2[4][4];               // out-proj accumulators, carried across halves
  #pragma unroll
  for (int c = 0; c < 4; ++c)
    #pragma unroll
    for (int rb = 0; rb < 4; ++rb)
      acc2[c][rb] = (f32x4){0.f, 0.f, 0.f, 0.f};

  #pragma unroll 1
  for (int hf = 0; hf < 2; ++hf) {
    // ---- Phase 1 (half hf): QKV GEMM for heads hf*4..hf*4+3.
    //      Wave w: Q col-blocks {2w,2w+1}, K {2w,2w+1}, V {2w,2w+1} (16 cols each).
    {
      f32x4 accq[2][4], acck[2][4], accv[2][4];
      #pragma unroll
      for (int j = 0; j < 2; ++j)
        #pragma unroll
        for (int rb = 0; rb < 4; ++rb) {
          accq[j][rb] = (f32x4){0.f, 0.f, 0.f, 0.f};
          acck[j][rb] = (f32x4){0.f, 0.f, 0.f, 0.f};
          accv[j][rb] = (f32x4){0.f, 0.f, 0.f, 0.f};
        }
      size_t oq[2], ok[2], ov[2];
      #pragma unroll
      for (int j = 0; j < 2; ++j) {
        const int cb = w * 2 + j;
        oq[j] = (size_t)(hf * 128 + cb * 16 + li) * 256;
        ok[j] = (size_t)(256 + hf * 128 + cb * 16 + li) * 256;
        ov[j] = (size_t)(512 + hf * 128 + cb * 16 + li) * 256;
      }

      #pragma unroll
      for (int kk = 0; kk < 8; ++kk) {
        s16x8 a[4];
        #pragma unroll
        for (int rb = 0; rb < 4; ++rb)
          a[rb] = *(const s16x8*)(lds + LDS_X + swz512(rb * 16 + li, kk * 64 + g * 16));
        s16x8 bq[2], bk[2], bv[2];
        #pragma unroll
        for (int j = 0; j < 2; ++j) {
          bq[j] = *(const s16x8*)(wqkvT + oq[j] + kk * 32 + g * 8);
          bk[j] = *(const s16x8*)(wqkvT + ok[j] + kk * 32 + g * 8);
          bv[j] = *(const s16x8*)(wqkvT + ov[j] + kk * 32 + g * 8);
        }
        #pragma unroll
        for (int j = 0; j < 2; ++j)
          #pragma unroll
          for (int rb = 0; rb < 4; ++rb) {
            accq[j][rb] = mfma16(bq[j], a[rb], accq[j][rb]);  // swapped: C[outcol][token]
            acck[j][rb] = mfma16(bk[j], a[rb], acck[j][rb]);
            accv[j][rb] = mfma16(a[rb], bv[j], accv[j][rb]);  // normal:  C[token][vcol]
          }
      }

      // Packed b64 stores into half-buffers.
      #pragma unroll
      for (int j = 0; j < 2; ++j) {
        const int cb = w * 2 + j;
        {   // Q (pre-scaled): row=token rb*16+li, 4 consecutive cols cb*16+g*4..
          f32x4 bq4 = *(const f32x4*)(bqkv + hf * 128 + cb * 16 + g * 4);
          const float SC = 0.17677669529663687f;
          #pragma unroll
          for (int rb = 0; rb < 4; ++rb) {
            u32x2 uu;
            uu.x = cvt2((accq[j][rb][0] + bq4[0]) * SC, (accq[j][rb][1] + bq4[1]) * SC);
            uu.y = cvt2((accq[j][rb][2] + bq4[2]) * SC, (accq[j][rb][3] + bq4[3]) * SC);
            *(u32x2*)(lds + LDS_Q + swz256(rb * 16 + li, cb * 32 + g * 8)) = uu;
          }
        }
        {   // K
          f32x4 bk4 = *(const f32x4*)(bqkv + 256 + hf * 128 + cb * 16 + g * 4);
          #pragma unroll
          for (int rb = 0; rb < 4; ++rb) {
            u32x2 uu;
            uu.x = cvt2(acck[j][rb][0] + bk4[0], acck[j][rb][1] + bk4[1]);
            uu.y = cvt2(acck[j][rb][2] + bk4[2], acck[j][rb][3] + bk4[3]);
            *(u32x2*)(lds + LDS_K + swz256(rb * 16 + li, cb * 32 + g * 8)) = uu;
          }
        }
        {   // V -> VT[d][token] fp16: row d = cb*16+li, 4 consecutive tokens
          const int d = cb * 16 + li;
          const float bv = bqkv[512 + hf * 128 + d];
          #pragma unroll
          for (int rb = 0; rb < 4; ++rb) {
            u32x2 uu;
            uu.x = cvt2h(accv[j][rb][0] + bv, accv[j][rb][1] + bv);
            uu.y = cvt2h(accv[j][rb][2] + bv, accv[j][rb][3] + bv);
            *(u32x2*)(lds + LDS_VT + swz128(d, rb * 32 + g * 8)) = uu;
          }
        }
      }
    }
    __syncthreads();

    // ---- Phase 2 (half hf): attention. Wave w = head w (within half), all 64 rows
    //      in two serial 32-row p-halves; K/V fragments shared across the two.
    //      In-register P'->PV (no LDS round-trip). ----
    {
      const int h = w;                 // head within half
      const int ah = hf * 4 + h;       // actual head

      s16x8 kf[4];
      #pragma unroll
      for (int qt = 0; qt < 4; ++qt)
        kf[qt] = *(const s16x8*)(lds + LDS_K + swz256(qt * 16 + li, h * 64 + g * 16));
      f16x4 vf[2][4];
      #pragma unroll
      for (int dt = 0; dt < 2; ++dt)
        #pragma unroll
        for (int qt = 0; qt < 4; ++qt)
          vf[dt][qt] = *(const f16x4*)(lds + LDS_VT
                                       + swz128(h * 32 + dt * 16 + li, qt * 32 + g * 8));

      #pragma unroll 1
      for (int ph = 0; ph < 2; ++ph) {
        const int p0 = ph * 32;

        f32x4 simT[2][4];
        #pragma unroll
        for (int pt = 0; pt < 2; ++pt) {
          s16x8 qf = *(const s16x8*)(lds + LDS_Q + swz256(p0 + pt * 16 + li, h * 64 + g * 16));
          #pragma unroll
          for (int qt = 0; qt < 4; ++qt) {
            f32x4 rc = *(const f32x4*)(relt
                + ((((rvar * 8 + ah) * 4 + qt) * 4 + (ph * 2 + pt)) * 64 + l) * 4);
            simT[pt][qt] = mfma16(kf[qt], qf, rc);
          }
        }

        float rinv[2];
        f16x4 pa[2][4];
        #pragma unroll
        for (int pt = 0; pt < 2; ++pt) {
          float s = 0.f;
          #pragma unroll
          for (int qt = 0; qt < 4; ++qt) {
            float e0 = __expf(simT[pt][qt][0]);
            float e1 = __expf(simT[pt][qt][1]);
            float e2 = __expf(simT[pt][qt][2]);
            float e3 = __expf(simT[pt][qt][3]);
            s += (e0 + e1) + (e2 + e3);
            pa[pt][qt] = pack4h(e0, e1, e2, e3);
          }
          s += __shfl_xor(s, 16);
          s += __shfl_xor(s, 32);
          rinv[pt] = 1.0f / s;
        }

        f32x4 at[2][2];
        #pragma unroll
        for (int pt = 0; pt < 2; ++pt)
          #pragma unroll
          for (int dt = 0; dt < 2; ++dt)
            at[pt][dt] = (f32x4){0.f, 0.f, 0.f, 0.f};
        #pragma unroll
        for (int qt = 0; qt < 4; ++qt)
          #pragma unroll
          for (int pt = 0; pt < 2; ++pt)
            #pragma unroll
            for (int dt = 0; dt < 2; ++dt)
              at[pt][dt] = mfmah16(vf[dt][qt], pa[pt][qt], at[pt][dt]);

        // attn fp16 store into Q region (own head columns, own rows -> no hazards)
        #pragma unroll
        for (int pt = 0; pt < 2; ++pt)
          #pragma unroll
          for (int dt = 0; dt < 2; ++dt) {
            const f32x4 a4 = at[pt][dt];
            u32x2 hh;
            hh.x = cvt2h(a4[0] * rinv[pt], a4[1] * rinv[pt]);
            hh.y = cvt2h(a4[2] * rinv[pt], a4[3] * rinv[pt]);
            *(u32x2*)(lds + LDS_Q + swz256(p0 + pt * 16 + li, h * 64 + dt * 32 + g * 8)) = hh;
          }
      }
    }
    __syncthreads();

    // ---- Phase 3 (half hf): partial out-proj (k = hf*128..+127), fp16.
    //      Wave w owns col-blocks w*4..w*4+3; accumulate into persistent acc2. ----
    {
      #pragma unroll
      for (int kk = 0; kk < 4; ++kk) {
        s16x8 a[4];
        #pragma unroll
        for (int rb = 0; rb < 4; ++rb)
          a[rb] = *(const s16x8*)(lds + LDS_Q + swz256(rb * 16 + li, kk * 64 + g * 16));
        #pragma unroll
        for (int c = 0; c < 4; ++c) {
          s16x8 bc = *(const s16x8*)(wH + (size_t)((w * 4 + c) * 16 + li) * 256
                                     + hf * 128 + kk * 32 + g * 8);
          #pragma unroll
          for (int rb = 0; rb < 4; ++rb)
            acc2[c][rb] = mfma16h(a[rb], bc, acc2[c][rb]);
        }
      }
    }
    if (hf == 0) __syncthreads();   // protect Q/K/VT before half-2 phase 1 overwrites
  }

  // ---- Epilogue: direct rolled stores (proven clean: WRITE == out size) ----
  #pragma unroll
  for (int c = 0; c < 4; ++c) {
    const int n = (w * 4 + c) * 16 + li;
    const float bo = bout[n];
    #pragma unroll
    for (int rb = 0; rb < 4; ++rb)
      #pragma unroll
      for (int r = 0; r < 4; ++r) {
        int m = rb * 16 + g * 4 + r;
        int pi = m >> 3, pj = m & 7;
        int dr = (wh * 8 + pi + 4) & 255;
        int dc = (wwi * 8 + pj + 4) & 255;
        out[(((size_t)b * 256 + dr) * 256 + dc) * 256 + n] = acc2[c][rb][r] + bo;
      }
  }
}

extern "C" void kernel_launch(void* const* d_in, const int* in_sizes, int n_in,
                              void* d_out, int out_size, void* d_ws, size_t ws_size,
                              hipStream_t stream) {
  (void)in_sizes; (void)n_in; (void)out_size; (void)ws_size;
  const float* x    = (const float*)d_in[0];
  const float* Wqkv = (const float*)d_in[1];
  const float* bqkv = (const float*)d_in[2];
  const float* relp = (const float*)d_in[3];
  const float* Wout = (const float*)d_in[4];
  const float* bout = (const float*)d_in[5];
  float* out = (float*)d_out;

  short* wqkvT = (short*)d_ws;                  // 768*256 bf16
  short* wH    = wqkvT + 768 * 256;             // 256*256 fp16
  float* relt  = (float*)(wH + 256 * 256);      // 4*8*4*4*256 f32 = 512KB

  hipLaunchKernelGGL(prep_w, dim3(1536), dim3(256), 0, stream,
                     Wqkv, Wout, relp, wqkvT, wH, relt);
  hipLaunchKernelGGL(swin_mfma, dim3(4096), dim3(256), 0, stream,
                     x, bqkv, bout, wqkvT, wH, relt, out);
}